// Round 8
// baseline (64.097 us; speedup 1.0000x reference)
//
#include <hip/hip_runtime.h>

#define THREADS 256
typedef float v2f __attribute__((ext_vector_type(2)));

// Pade(7,6) tanh on clamped |x|<=5:
//   tanh(x) ~= x*(x^6+378x^4+17325x^2+135135) / (28x^6+3150x^4+62370x^2+135135)
// (from the tanh continued fraction; exact to 6 digits at x=1, max err ~1e-4 at the
// clamp seam — far inside harness tolerance). 4 elements share ONE v_rcp_f32 via
// batched reciprocal: TRANS per sample drops 132 -> 27.
__device__ __forceinline__ void tanh4(v2f a, v2f b, float* y0, float* y1,
                                      float* y2, float* y3) {
    const v2f C = {5.0f, 5.0f}, Cn = {-5.0f, -5.0f};
    a = __builtin_elementwise_min(__builtin_elementwise_max(a, Cn), C);
    b = __builtin_elementwise_min(__builtin_elementwise_max(b, Cn), C);
    v2f a2 = a * a, b2 = b * b;
    v2f pa = a * (135135.0f + a2 * (17325.0f + a2 * (378.0f + a2)));
    v2f pb = b * (135135.0f + b2 * (17325.0f + b2 * (378.0f + b2)));
    v2f qa = 135135.0f + a2 * (62370.0f + a2 * (3150.0f + a2 * 28.0f));
    v2f qb = 135135.0f + b2 * (62370.0f + b2 * (3150.0f + b2 * 28.0f));
    // batched reciprocal of qa.x, qa.y, qb.x, qb.y  (q in [1.35e5, 4.1e6]: no overflow)
    float t01 = qa.x * qa.y, t23 = qb.x * qb.y;
    float I   = __builtin_amdgcn_rcpf(t01 * t23);
    float I01 = I * t23, I23 = I * t01;
    v2f ra = { I01 * qa.y, I01 * qa.x };
    v2f rb = { I23 * qb.y, I23 * qb.x };
    v2f ya = pa * ra, yb = pb * rb;
    *y0 = ya.x; *y1 = ya.y; *y2 = yb.x; *y3 = yb.y;
}

// y[j] = tanh(b[j] + sum_k x[k]*W[k][j]); OUT % 4 == 0; packed v_pk_fma_f32
template<int IN, int OUT>
__device__ __forceinline__ void dense(const float* x, float* y,
                                      const float* __restrict__ W,
                                      const float* __restrict__ b) {
#pragma unroll
    for (int j = 0; j < OUT; j += 4) {
        v2f a01 = { b[j],     b[j + 1] };
        v2f a23 = { b[j + 2], b[j + 3] };
#pragma unroll
        for (int k = 0; k < IN; ++k) {
            v2f w01 = { W[k * OUT + j],     W[k * OUT + j + 1] };
            v2f w23 = { W[k * OUT + j + 2], W[k * OUT + j + 3] };
            a01 += w01 * x[k];
            a23 += w23 * x[k];
        }
        tanh4(a01, a23, &y[j], &y[j + 1], &y[j + 2], &y[j + 3]);
    }
}

__global__ __launch_bounds__(THREADS) void qcnn_fused(
        const float* __restrict__ inputs,
        const float* __restrict__ W_fm, const float* __restrict__ b_fm,
        const float* __restrict__ W1,  const float* __restrict__ b1,
        const float* __restrict__ Wp1, const float* __restrict__ bp1,
        const float* __restrict__ W2,  const float* __restrict__ b2,
        const float* __restrict__ Wp2, const float* __restrict__ bp2,
        const float* __restrict__ W3,  const float* __restrict__ b3,
        const float* __restrict__ protos,
        const float* __restrict__ Wh,  const float* __restrict__ bh,
        float* __restrict__ out, int B) {
    const int tid = blockIdx.x * THREADS + threadIdx.x;
    if (tid >= B) return;

    float xa[16], xb[16];

    const float4* in4 = reinterpret_cast<const float4*>(inputs) + (size_t)tid * 2;
    float4 v0 = in4[0], v1 = in4[1];
    xa[0] = v0.x; xa[1] = v0.y; xa[2] = v0.z; xa[3] = v0.w;
    xa[4] = v1.x; xa[5] = v1.y; xa[6] = v1.z; xa[7] = v1.w;

    dense<8, 16>(xa, xb, W_fm, b_fm);  // feature_map
    dense<16, 16>(xb, xa, W1, b1);     // conv1
    dense<16, 12>(xa, xb, Wp1, bp1);   // pool1
    dense<12, 8>(xb, xa, W2, b2);      // conv2
    dense<8, 4>(xa, xb, Wp2, bp2);     // pool2
    dense<4, 4>(xb, xa, W3, b3);       // conv3 -> xa[0..3]

    // head contribution of x, then RBF features vs 10 prototypes (GAMMA = 1)
    v2f ha = { bh[0], 0.0f };
    ha += (v2f){ xa[0], xa[1] } * (v2f){ Wh[0], Wh[1] };
    ha += (v2f){ xa[2], xa[3] } * (v2f){ Wh[2], Wh[3] };
    float acc = ha.x + ha.y;

#pragma unroll
    for (int j = 0; j < 10; j += 2) {
        v2f d2 = { 0.0f, 0.0f };
#pragma unroll
        for (int k = 0; k < 4; ++k) {
            v2f p = { protos[j * 4 + k], protos[(j + 1) * 4 + k] };
            v2f d = (v2f){ xa[k], xa[k] } - p;
            d2 += d * d;
        }
        v2f d2s = d2 * -1.4426950408889634f;        // -log2e
        float kf0 = __builtin_amdgcn_exp2f(d2s.x);  // exp(-d2)
        float kf1 = __builtin_amdgcn_exp2f(d2s.y);
        acc = fmaf(kf0, Wh[4 + j], acc);
        acc = fmaf(kf1, Wh[5 + j], acc);
    }
    // sigmoid
    float e = __builtin_amdgcn_exp2f(acc * -1.4426950408889634f);
    out[tid] = __builtin_amdgcn_rcpf(1.0f + e);
}

extern "C" void kernel_launch(void* const* d_in, const int* in_sizes, int n_in,
                              void* d_out, int out_size, void* d_ws, size_t ws_size,
                              hipStream_t stream) {
    const float* inputs = (const float*)d_in[0];
    float* out = (float*)d_out;
    const int B = in_sizes[0] / 8;
    const int blocks = (B + THREADS - 1) / THREADS;
    qcnn_fused<<<blocks, THREADS, 0, stream>>>(
        inputs,
        (const float*)d_in[1],  (const float*)d_in[2],
        (const float*)d_in[3],  (const float*)d_in[4],
        (const float*)d_in[5],  (const float*)d_in[6],
        (const float*)d_in[7],  (const float*)d_in[8],
        (const float*)d_in[9],  (const float*)d_in[10],
        (const float*)d_in[11], (const float*)d_in[12],
        (const float*)d_in[13],
        (const float*)d_in[14], (const float*)d_in[15],
        out, B);
}